// Round 2
// baseline (478.911 us; speedup 1.0000x reference)
//
#include <hip/hip_runtime.h>
#include <hip/hip_bf16.h>
#include <cstdint>
#include <cstddef>

typedef __bf16 bf16_t;
typedef __bf16 bf16x8 __attribute__((ext_vector_type(8)));
typedef float f32x4 __attribute__((ext_vector_type(4)));

#define TOKENS 8192
#define IN_F 4096
#define OUT_F 4096

// fallback (128^2) geometry
#define BM 128
#define BN 128
#define BK 32

// 8-phase (256^2) geometry
#define GK 64
#define NT (IN_F / GK)   // 64 K-tiles

// async global->LDS, 16B per lane; LDS dest is wave-uniform base + lane*16
#define GLDS(gp, lp)                                                      \
  __builtin_amdgcn_global_load_lds(                                       \
      (__attribute__((address_space(1))) void*)(gp),                      \
      (__attribute__((address_space(3))) void*)(lp), 16, 0, 0)

#define SB0() __builtin_amdgcn_sched_barrier(0)

// ---------------- dequant: packed nibbles -> bf16 W[OUT_F][IN_F] ----------
__global__ __launch_bounds__(256) void dequant_nf4(
    const int* __restrict__ qw, const int* __restrict__ am1,
    const float* __restrict__ cd1, const float* __restrict__ of1,
    const float* __restrict__ am2, const float* __restrict__ cd2,
    bf16_t* __restrict__ W) {
  const int t = blockIdx.x * 256 + threadIdx.x;
  const int e0 = t << 3;        // 8 dequantized elements per thread
  const int b1 = e0 >> 6;       // primary block (64 elems) -- all 8 share it
  const int b2 = e0 >> 8;       // secondary block (256 elems)
  const int4 v = *(const int4*)(qw + (t << 2));
  const float s2 = am2[b2] / cd2[b2];
  const float s1 = ((float)am1[b1] / cd1[b1]) * s2;
  const float off = of1[b1];
  int vv[4] = {v.x, v.y, v.z, v.w};
  bf16x8 w;
#pragma unroll
  for (int i = 0; i < 4; ++i) {
    w[2 * i]     = (bf16_t)(((float)(vv[i] & 15) - off) * s1);
    w[2 * i + 1] = (bf16_t)(((float)((vv[i] >> 4) & 15) - off) * s1);
  }
  *(bf16x8*)(W + e0) = w;
}

// ---------------- X: f32 -> bf16 one-shot convert -------------------------
__global__ __launch_bounds__(256) void conv_x(
    const float* __restrict__ X, bf16_t* __restrict__ Xb) {
  const size_t e0 = ((size_t)blockIdx.x * 256 + threadIdx.x) << 3;
  f32x4 a = *(const f32x4*)(X + e0);
  f32x4 b = *(const f32x4*)(X + e0 + 4);
  bf16x8 w;
#pragma unroll
  for (int i = 0; i < 4; ++i) {
    w[i] = (bf16_t)a[i];
    w[i + 4] = (bf16_t)b[i];
  }
  *(bf16x8*)(Xb + e0) = w;
}

// ======== GEMM (fast): 256x256 tile, BK=64, 8-wave, phase schedule ========
// m201 template + deep prefetch: T1 XCD swizzle + T2 st_16x32 LDS swizzle +
// T3/T4 counted-vmcnt pipeline + T5 setprio. C[M,N] = Xb[M,K]*W[N,K]^T.
//
// LDS (128 KiB): A[2 buf][2 half][16 subtile][512], B same.
//   half = 128 rows x 64 cols bf16; subtile = 16x32 elems = 1024 B, stored
//   contiguous; within subtile byte ^= ((byte>>9)&1)<<5 (st_16x32).
// Staging: one global_load_lds (64 lanes x 16 B) = exactly one subtile row
//   group; LDS dest linear, global SOURCE pre-swizzled (rule #21).
// Schedule per K-tile t (buf b=t&1):
//   phase 0: 12 ds_reads; stage A(t+1) h0+h1 (4 GLDS); MFMA acc[0..3][0..1]
//   phase 1:  4 ds_reads; stage B(t+1) h0+h1 (4 GLDS); MFMA acc[0..3][2..3]
//   phase 2:  8 ds_reads; MFMA acc[4..7][0..3] (32 MFMA, merged ph2+3);
//             vmcnt(0) at boundary -- every t+1 load has had >=2.5 phases
//             (~3000 cyc) to land, so the drain is satisfied, not a stall.
// Buf b^1 is write-legal from tile-t phase 0: tile t-1's last ds_reads
// completed behind its phase-2 lgkmcnt(0) + two barriers.
__global__ __launch_bounds__(512) void gemm_8p(
    const bf16_t* __restrict__ X, const bf16_t* __restrict__ Wq,
    float* __restrict__ C) {
  __shared__ __align__(16) bf16_t smem[65536];   // 128 KiB
  bf16_t* const As = smem;            // 32768 elems = 2 bufs x 16384
  bf16_t* const Bs = smem + 32768;

  const int tid  = threadIdx.x;
  const int l    = tid & 63;
  const int w    = tid >> 6;          // 8 waves
  const int wm   = w >> 2;            // 2 along M (128 rows each)
  const int wn   = w & 3;             // 4 along N (64 cols each)
  const int lr   = l & 15;
  const int quad = l >> 4;

  // T1: XCD-aware bijective swizzle (nwg=512, 512%8==0)
  const int swz = (blockIdx.x & 7) * 64 + (blockIdx.x >> 3);
  const int m0 = (swz >> 4) * 256;    // 32 m-tiles
  const int n0 = (swz & 15) * 256;    // 16 n-tiles

  // ---- staging addressing: wave w covers rows 16*(w>>1)..+15 per GLDS,
  // cols 32*(w&1)..+31; lane l -> row +l/4, col (8*(l&3)) ^ (l>=32?16:0)
  // [inverse st_16x32 swizzle on the global source]
  const int grow = ((w >> 1) << 4) + (l >> 2);
  const int gcol = ((w & 1) << 5) + (((l & 3) << 3) ^ ((l & 32) ? 16 : 0));
  const bf16_t* const gA = X  + (size_t)(m0 + grow) * IN_F + gcol;
  const bf16_t* const gB = Wq + (size_t)(n0 + grow) * IN_F + gcol;
  const int ldsw = w << 9;            // wave-uniform LDS elem offset (w*512)

  auto stageA = [&](int kt, int h) {
    const bf16_t* s = gA + (size_t)(h * 128) * IN_F + kt * GK;
    bf16_t* d = As + ((kt & 1) << 14) + (h << 13) + ldsw;
    GLDS(s, d);
    GLDS(s + (size_t)64 * IN_F, d + 4096);
  };
  auto stageB = [&](int kt, int h) {
    const bf16_t* s = gB + (size_t)(h * 128) * IN_F + kt * GK;
    bf16_t* d = Bs + ((kt & 1) << 14) + (h << 13) + ldsw;
    GLDS(s, d);
    GLDS(s + (size_t)64 * IN_F, d + 4096);
  };

  // ---- read addressing (byte offsets; swizzled) ----
  // frag (i,ks): subtile (R=i, Cb=ks) of wave's half; lane reads row lr,
  // cols ks*32+quad*8..+7 -> byte (lr*64 + quad*16) ^ ((lr&8)?32:0)
  const int rdoff = ((lr << 6) + (quad << 4)) ^ ((lr & 8) ? 32 : 0);
  const char* const aRd = (const char*)As + (wm << 14) + rdoff;
  const char* const bRd =
      (const char*)Bs + ((wn >> 1) << 14) + ((wn & 1) << 13) + rdoff;

#define RDA(b, i, ks) \
  (*(const bf16x8*)(aRd + ((b) << 15) + ((((i) << 1) + (ks)) << 10)))
#define RDB(b, j, ks) \
  (*(const bf16x8*)(bRd + ((b) << 15) + ((((j) << 1) + (ks)) << 10)))

  f32x4 acc[8][4];
#pragma unroll
  for (int i = 0; i < 8; ++i)
#pragma unroll
    for (int j = 0; j < 4; ++j) acc[i][j] = (f32x4){0.f, 0.f, 0.f, 0.f};

  bf16x8 fa[4][2], fb[4][2];

  // ---- prologue: stage tile 0 fully; drain; barrier
  stageA(0, 0); stageA(0, 1); stageB(0, 0); stageB(0, 1);
  asm volatile("s_waitcnt vmcnt(0)" ::: "memory");
  __builtin_amdgcn_s_barrier();

  for (int t = 0; t < NT; ++t) {
    const int b = t & 1;
    const int kt1 = t + 1;
    const bool pf = (kt1 < NT);

    // ---- phase 0: 12 ds_reads; stage A(t+1) h0+h1; MFMA acc[0..3][0..1] --
#pragma unroll
    for (int i = 0; i < 4; ++i) {
      fa[i][0] = RDA(b, i, 0);
      fa[i][1] = RDA(b, i, 1);
    }
#pragma unroll
    for (int j = 0; j < 2; ++j) {
      fb[j][0] = RDB(b, j, 0);
      fb[j][1] = RDB(b, j, 1);
    }
    if (pf) { stageA(kt1, 0); stageA(kt1, 1); }
    asm volatile("s_waitcnt lgkmcnt(8)" ::: "memory");
    SB0();
    __builtin_amdgcn_s_barrier();
    asm volatile("s_waitcnt lgkmcnt(0)" ::: "memory");
    SB0();
    __builtin_amdgcn_s_setprio(1);
#pragma unroll
    for (int ks = 0; ks < 2; ++ks)
#pragma unroll
      for (int i = 0; i < 4; ++i)
#pragma unroll
        for (int j = 0; j < 2; ++j)
          acc[i][j] = __builtin_amdgcn_mfma_f32_16x16x32_bf16(
              fa[i][ks], fb[j][ks], acc[i][j], 0, 0, 0);
    __builtin_amdgcn_s_setprio(0);
    SB0();
    __builtin_amdgcn_s_barrier();

    // ---- phase 1: 4 ds_reads; stage B(t+1) h0+h1; MFMA acc[0..3][2..3] --
#pragma unroll
    for (int j = 0; j < 2; ++j) {
      fb[j + 2][0] = RDB(b, j + 2, 0);
      fb[j + 2][1] = RDB(b, j + 2, 1);
    }
    if (pf) { stageB(kt1, 0); stageB(kt1, 1); }
    SB0();
    __builtin_amdgcn_s_barrier();
    asm volatile("s_waitcnt lgkmcnt(0)" ::: "memory");
    SB0();
    __builtin_amdgcn_s_setprio(1);
#pragma unroll
    for (int ks = 0; ks < 2; ++ks)
#pragma unroll
      for (int i = 0; i < 4; ++i)
#pragma unroll
        for (int j = 0; j < 2; ++j)
          acc[i][j + 2] = __builtin_amdgcn_mfma_f32_16x16x32_bf16(
              fa[i][ks], fb[j + 2][ks], acc[i][j + 2], 0, 0, 0);
    __builtin_amdgcn_s_setprio(0);
    SB0();
    __builtin_amdgcn_s_barrier();

    // ---- phase 2 (merged 2+3): 8 ds_reads (fa <- rows 64..127);
    //      MFMA acc[4..7][0..3] (32 back-to-back); boundary vmcnt(0) ----
#pragma unroll
    for (int i = 0; i < 4; ++i) {
      fa[i][0] = RDA(b, i + 4, 0);
      fa[i][1] = RDA(b, i + 4, 1);
    }
    SB0();
    __builtin_amdgcn_s_barrier();
    asm volatile("s_waitcnt lgkmcnt(0)" ::: "memory");
    SB0();
    __builtin_amdgcn_s_setprio(1);
#pragma unroll
    for (int ks = 0; ks < 2; ++ks)
#pragma unroll
      for (int i = 0; i < 4; ++i)
#pragma unroll
        for (int j = 0; j < 2; ++j)
          acc[i + 4][j] = __builtin_amdgcn_mfma_f32_16x16x32_bf16(
              fa[i][ks], fb[j][ks], acc[i + 4][j], 0, 0, 0);
#pragma unroll
    for (int ks = 0; ks < 2; ++ks)
#pragma unroll
      for (int i = 0; i < 4; ++i)
#pragma unroll
        for (int j = 0; j < 2; ++j)
          acc[i + 4][j + 2] = __builtin_amdgcn_mfma_f32_16x16x32_bf16(
              fa[i][ks], fb[j + 2][ks], acc[i + 4][j + 2], 0, 0, 0);
    __builtin_amdgcn_s_setprio(0);
    SB0();
    asm volatile("s_waitcnt vmcnt(0)" ::: "memory");
    __builtin_amdgcn_s_barrier();
  }

  // epilogue: C/D layout col=lane&15, row=quad*4+reg; f32 out
  const int r0 = m0 + (wm << 7) + (quad << 2);
  const int c0 = n0 + (wn << 6) + lr;
#pragma unroll
  for (int i = 0; i < 8; ++i)
#pragma unroll
    for (int j = 0; j < 4; ++j)
#pragma unroll
      for (int r = 0; r < 4; ++r)
        C[(size_t)(r0 + i * 16 + r) * OUT_F + (c0 + j * 16)] = acc[i][j][r];
#undef RDA
#undef RDB
}

// ------- GEMM (fallback, round-3 passing kernel): X f32, W bf16 -----------
__global__ __launch_bounds__(256) void gemm_fb(
    const float* __restrict__ X, const bf16_t* __restrict__ W,
    float* __restrict__ C) {
  __shared__ __align__(16) bf16_t Asf[BM * BK];
  __shared__ __align__(16) bf16_t Bsf[BN * BK];

  const int tid = threadIdx.x;
  const int lane = tid & 63;
  const int wid = tid >> 6;
  const int m0 = blockIdx.y * BM;
  const int n0 = blockIdx.x * BN;

  const int srow = tid >> 2;
  const int sk = (tid & 3) << 3;
  const float* ag0 = X + (size_t)(m0 + srow) * IN_F + sk;
  const float* ag1 = ag0 + (size_t)64 * IN_F;
  const bf16_t* bg0 = W + (size_t)(n0 + srow) * IN_F + sk;
  const bf16_t* bg1 = bg0 + (size_t)64 * IN_F;
  bf16_t* as0 = Asf + srow * BK + sk;
  bf16_t* as1 = as0 + 64 * BK;
  bf16_t* bs0 = Bsf + srow * BK + sk;
  bf16_t* bs1 = bs0 + 64 * BK;

  const int wmf = (wid >> 1) << 6;
  const int wnf = (wid & 1) << 6;
  const int lrf = lane & 15;
  const int quadf = lane >> 4;

  f32x4 acc[4][4] = {};

  for (int k0 = 0; k0 < IN_F; k0 += BK) {
    f32x4 xa0 = *(const f32x4*)(ag0 + k0);
    f32x4 xa1 = *(const f32x4*)(ag0 + k0 + 4);
    f32x4 xb0 = *(const f32x4*)(ag1 + k0);
    f32x4 xb1 = *(const f32x4*)(ag1 + k0 + 4);
    bf16x8 rb0 = *(const bf16x8*)(bg0 + k0);
    bf16x8 rb1 = *(const bf16x8*)(bg1 + k0);

    bf16x8 ra0, ra1;
#pragma unroll
    for (int t = 0; t < 4; ++t) {
      ra0[t] = (bf16_t)xa0[t];
      ra0[t + 4] = (bf16_t)xa1[t];
      ra1[t] = (bf16_t)xb0[t];
      ra1[t + 4] = (bf16_t)xb1[t];
    }

    __syncthreads();
    *(bf16x8*)as0 = ra0;
    *(bf16x8*)as1 = ra1;
    *(bf16x8*)bs0 = rb0;
    *(bf16x8*)bs1 = rb1;
    __syncthreads();

    bf16x8 fa[4], fbv[4];
#pragma unroll
    for (int i = 0; i < 4; ++i)
      fa[i] = *(const bf16x8*)(Asf + (wmf + i * 16 + lrf) * BK + quadf * 8);
#pragma unroll
    for (int j = 0; j < 4; ++j)
      fbv[j] = *(const bf16x8*)(Bsf + (wnf + j * 16 + lrf) * BK + quadf * 8);

#pragma unroll
    for (int i = 0; i < 4; ++i)
#pragma unroll
      for (int j = 0; j < 4; ++j)
        acc[i][j] = __builtin_amdgcn_mfma_f32_16x16x32_bf16(
            fa[i], fbv[j], acc[i][j], 0, 0, 0);
  }

#pragma unroll
  for (int i = 0; i < 4; ++i)
#pragma unroll
    for (int j = 0; j < 4; ++j)
#pragma unroll
      for (int r = 0; r < 4; ++r) {
        const int row = m0 + wmf + i * 16 + (quadf << 2) + r;
        const int col = n0 + wnf + j * 16 + lrf;
        C[(size_t)row * OUT_F + col] = acc[i][j][r];
      }
}

extern "C" void kernel_launch(void* const* d_in, const int* in_sizes, int n_in,
                              void* d_out, int out_size, void* d_ws, size_t ws_size,
                              hipStream_t stream) {
  const float* x   = (const float*)d_in[0];   // fp16 in reference -> f32 here
  const int* qw    = (const int*)d_in[1];
  const int* am1   = (const int*)d_in[2];
  const float* cd1 = (const float*)d_in[3];
  const float* of1 = (const float*)d_in[4];
  const float* am2 = (const float*)d_in[5];
  const float* cd2 = (const float*)d_in[6];
  float* out = (float*)d_out;                 // fp16 in reference -> f32 here

  const size_t W_BYTES  = (size_t)OUT_F * IN_F * 2;   // 32 MiB
  const size_t XB_BYTES = (size_t)TOKENS * IN_F * 2;  // 64 MiB
  bf16_t* W = (bf16_t*)d_ws;

  dequant_nf4<<<dim3((OUT_F * IN_F) / 8 / 256), dim3(256), 0, stream>>>(
      qw, am1, cd1, of1, am2, cd2, W);

  if (ws_size >= W_BYTES + XB_BYTES) {
    // fast path: pre-convert X to bf16, 256^2 8-phase GEMM (m201 template)
    bf16_t* Xb = (bf16_t*)((char*)d_ws + W_BYTES);
    conv_x<<<dim3((TOKENS * IN_F) / 8 / 256), dim3(256), 0, stream>>>(x, Xb);
    gemm_8p<<<dim3((TOKENS / 256) * (OUT_F / 256)), dim3(512), 0, stream>>>(
        Xb, W, out);
  } else {
    // fallback: round-3 passing kernel (f32 X converted at staging)
    dim3 grid(OUT_F / BN, TOKENS / BM);
    gemm_fb<<<grid, dim3(256), 0, stream>>>(x, W, out);
  }
}

// Round 3
// 469.810 us; speedup vs baseline: 1.0194x; 1.0194x over previous
//
#include <hip/hip_runtime.h>
#include <hip/hip_bf16.h>
#include <cstdint>
#include <cstddef>

typedef __bf16 bf16_t;
typedef __bf16 bf16x8 __attribute__((ext_vector_type(8)));
typedef float f32x4 __attribute__((ext_vector_type(4)));

#define TOKENS 8192
#define IN_F 4096
#define OUT_F 4096

// fallback (128^2) geometry
#define BM 128
#define BN 128
#define BK 32

// 8-phase (256^2) geometry
#define GK 64
#define NT (IN_F / GK)   // 64 K-tiles

// async global->LDS, 16B per lane; LDS dest is wave-uniform base + lane*16
#define GLDS(gp, lp)                                                      \
  __builtin_amdgcn_global_load_lds(                                       \
      (__attribute__((address_space(1))) void*)(gp),                      \
      (__attribute__((address_space(3))) void*)(lp), 16, 0, 0)

#define SB0() __builtin_amdgcn_sched_barrier(0)

// ---------------- dequant: packed nibbles -> bf16 W[OUT_F][IN_F] ----------
__global__ __launch_bounds__(256) void dequant_nf4(
    const int* __restrict__ qw, const int* __restrict__ am1,
    const float* __restrict__ cd1, const float* __restrict__ of1,
    const float* __restrict__ am2, const float* __restrict__ cd2,
    bf16_t* __restrict__ W) {
  const int t = blockIdx.x * 256 + threadIdx.x;
  const int e0 = t << 3;        // 8 dequantized elements per thread
  const int b1 = e0 >> 6;       // primary block (64 elems) -- all 8 share it
  const int b2 = e0 >> 8;       // secondary block (256 elems)
  const int4 v = *(const int4*)(qw + (t << 2));
  const float s2 = am2[b2] / cd2[b2];
  const float s1 = ((float)am1[b1] / cd1[b1]) * s2;
  const float off = of1[b1];
  int vv[4] = {v.x, v.y, v.z, v.w};
  bf16x8 w;
#pragma unroll
  for (int i = 0; i < 4; ++i) {
    w[2 * i]     = (bf16_t)(((float)(vv[i] & 15) - off) * s1);
    w[2 * i + 1] = (bf16_t)(((float)((vv[i] >> 4) & 15) - off) * s1);
  }
  *(bf16x8*)(W + e0) = w;
}

// ---------------- X: f32 -> bf16 one-shot convert -------------------------
__global__ __launch_bounds__(256) void conv_x(
    const float* __restrict__ X, bf16_t* __restrict__ Xb) {
  const size_t e0 = ((size_t)blockIdx.x * 256 + threadIdx.x) << 3;
  f32x4 a = *(const f32x4*)(X + e0);
  f32x4 b = *(const f32x4*)(X + e0 + 4);
  bf16x8 w;
#pragma unroll
  for (int i = 0; i < 4; ++i) {
    w[i] = (bf16_t)a[i];
    w[i + 4] = (bf16_t)b[i];
  }
  *(bf16x8*)(Xb + e0) = w;
}

// ======== GEMM (fast): 256x256 tile, BK=64, 8-wave, 4-phase/tile ==========
// m201 template + B-early-stagger deep prefetch. C[M,N] = Xb[M,K]*W[N,K]^T.
//
// LDS (128 KiB): A[2 buf][2 half][16 subtile][512], B same.
//   half = 128 rows x 64 cols bf16; subtile = 16x32 = 1024 B contiguous;
//   within subtile byte ^= ((byte>>9)&1)<<5 (st_16x32). GLDS dest linear,
//   global SOURCE pre-swizzled (rule #21).
// Key scheduling fact: B frags are ds_read only in phases 0-1 (held in regs
// for phases 2-3), so tile t's B LDS region is dead after p1's lgkmcnt(0).
// => stage B(t+2) into buf b during tile t's p2/p3 (WAR-safe behind p1's
// closing barrier), A(t+1) into buf b^1 at p0/p1. Boundary wait = vmcnt(4)
// (keeps B(t+2)'s 4 loads in flight); youngest drained load (A-h1 @ p1)
// has ~2.5 phases (~3000 cyc) to land; B(t+1) had 5-6 phases. Uniform
// 2 GLDS/phase staging rhythm (round-1-proven).
__global__ __launch_bounds__(512) void gemm_8p(
    const bf16_t* __restrict__ X, const bf16_t* __restrict__ Wq,
    float* __restrict__ C) {
  __shared__ __align__(16) bf16_t smem[65536];   // 128 KiB
  bf16_t* const As = smem;            // 32768 elems = 2 bufs x 16384
  bf16_t* const Bs = smem + 32768;

  const int tid  = threadIdx.x;
  const int l    = tid & 63;
  const int w    = tid >> 6;          // 8 waves
  const int wm   = w >> 2;            // 2 along M (128 rows each)
  const int wn   = w & 3;             // 4 along N (64 cols each)
  const int lr   = l & 15;
  const int quad = l >> 4;

  // T1: XCD-aware bijective swizzle (nwg=512, 512%8==0)
  const int swz = (blockIdx.x & 7) * 64 + (blockIdx.x >> 3);
  const int m0 = (swz >> 4) * 256;    // 32 m-tiles
  const int n0 = (swz & 15) * 256;    // 16 n-tiles

  // ---- staging addressing: wave w covers rows 16*(w>>1)..+15 per GLDS,
  // cols 32*(w&1)..+31; lane l -> row +l/4, col (8*(l&3)) ^ (l>=32?16:0)
  // [inverse st_16x32 swizzle on the global source]
  const int grow = ((w >> 1) << 4) + (l >> 2);
  const int gcol = ((w & 1) << 5) + (((l & 3) << 3) ^ ((l & 32) ? 16 : 0));
  const bf16_t* const gA = X  + (size_t)(m0 + grow) * IN_F + gcol;
  const bf16_t* const gB = Wq + (size_t)(n0 + grow) * IN_F + gcol;
  const int ldsw = w << 9;            // wave-uniform LDS elem offset (w*512)

  auto stageA = [&](int kt, int h) {
    const bf16_t* s = gA + (size_t)(h * 128) * IN_F + kt * GK;
    bf16_t* d = As + ((kt & 1) << 14) + (h << 13) + ldsw;
    GLDS(s, d);
    GLDS(s + (size_t)64 * IN_F, d + 4096);
  };
  auto stageB = [&](int kt, int h) {
    const bf16_t* s = gB + (size_t)(h * 128) * IN_F + kt * GK;
    bf16_t* d = Bs + ((kt & 1) << 14) + (h << 13) + ldsw;
    GLDS(s, d);
    GLDS(s + (size_t)64 * IN_F, d + 4096);
  };

  // ---- read addressing (byte offsets; swizzled) ----
  // frag (i,ks): subtile (R=i, Cb=ks) of wave's half; lane reads row lr,
  // cols ks*32+quad*8..+7 -> byte (lr*64 + quad*16) ^ ((lr&8)?32:0)
  const int rdoff = ((lr << 6) + (quad << 4)) ^ ((lr & 8) ? 32 : 0);
  const char* const aRd = (const char*)As + (wm << 14) + rdoff;
  const char* const bRd =
      (const char*)Bs + ((wn >> 1) << 14) + ((wn & 1) << 13) + rdoff;

#define RDA(b, i, ks) \
  (*(const bf16x8*)(aRd + ((b) << 15) + ((((i) << 1) + (ks)) << 10)))
#define RDB(b, j, ks) \
  (*(const bf16x8*)(bRd + ((b) << 15) + ((((j) << 1) + (ks)) << 10)))

  f32x4 acc[8][4];
#pragma unroll
  for (int i = 0; i < 8; ++i)
#pragma unroll
    for (int j = 0; j < 4; ++j) acc[i][j] = (f32x4){0.f, 0.f, 0.f, 0.f};

  bf16x8 fa[4][2], fb[4][2];

  // ---- prologue: stage tile 0 fully + B(1); vmcnt(4) leaves B(1) in flight
  stageA(0, 0); stageA(0, 1); stageB(0, 0); stageB(0, 1);
  stageB(1, 0); stageB(1, 1);
  asm volatile("s_waitcnt vmcnt(4)" ::: "memory");
  __builtin_amdgcn_s_barrier();

  for (int t = 0; t < NT; ++t) {
    const int b = t & 1;
    const int kt1 = t + 1;               // A prefetch target (buf b^1)
    const int kt2 = t + 2;               // B prefetch target (buf b)
    const bool pfA = (kt1 < NT);
    const bool pfB = (kt2 < NT);

    // ---- phase 0: 12 ds_reads; stage A-h0(t+1); MFMA acc[0..3][0..1] ----
#pragma unroll
    for (int i = 0; i < 4; ++i) {
      fa[i][0] = RDA(b, i, 0);
      fa[i][1] = RDA(b, i, 1);
    }
#pragma unroll
    for (int j = 0; j < 2; ++j) {
      fb[j][0] = RDB(b, j, 0);
      fb[j][1] = RDB(b, j, 1);
    }
    if (pfA) stageA(kt1, 0);
    asm volatile("s_waitcnt lgkmcnt(8)" ::: "memory");
    SB0();
    __builtin_amdgcn_s_barrier();
    asm volatile("s_waitcnt lgkmcnt(0)" ::: "memory");
    SB0();
    __builtin_amdgcn_s_setprio(1);
#pragma unroll
    for (int ks = 0; ks < 2; ++ks)
#pragma unroll
      for (int i = 0; i < 4; ++i)
#pragma unroll
        for (int j = 0; j < 2; ++j)
          acc[i][j] = __builtin_amdgcn_mfma_f32_16x16x32_bf16(
              fa[i][ks], fb[j][ks], acc[i][j], 0, 0, 0);
    __builtin_amdgcn_s_setprio(0);
    SB0();
    __builtin_amdgcn_s_barrier();

    // ---- phase 1: 4 ds_reads; stage A-h1(t+1); MFMA acc[0..3][2..3] ----
#pragma unroll
    for (int j = 0; j < 2; ++j) {
      fb[j + 2][0] = RDB(b, j + 2, 0);
      fb[j + 2][1] = RDB(b, j + 2, 1);
    }
    if (pfA) stageA(kt1, 1);
    SB0();
    __builtin_amdgcn_s_barrier();
    asm volatile("s_waitcnt lgkmcnt(0)" ::: "memory");
    SB0();
    __builtin_amdgcn_s_setprio(1);
#pragma unroll
    for (int ks = 0; ks < 2; ++ks)
#pragma unroll
      for (int i = 0; i < 4; ++i)
#pragma unroll
        for (int j = 0; j < 2; ++j)
          acc[i][j + 2] = __builtin_amdgcn_mfma_f32_16x16x32_bf16(
              fa[i][ks], fb[j + 2][ks], acc[i][j + 2], 0, 0, 0);
    __builtin_amdgcn_s_setprio(0);
    SB0();
    __builtin_amdgcn_s_barrier();
    // from here tile t's B LDS region (buf b) is dead -> B(t+2) may land

    // ---- phase 2: 8 ds_reads (fa <- rows 64..127); stage B-h0(t+2);
    //      MFMA acc[4..7][0..1] ----
#pragma unroll
    for (int i = 0; i < 4; ++i) {
      fa[i][0] = RDA(b, i + 4, 0);
      fa[i][1] = RDA(b, i + 4, 1);
    }
    if (pfB) stageB(kt2, 0);
    SB0();
    __builtin_amdgcn_s_barrier();
    asm volatile("s_waitcnt lgkmcnt(0)" ::: "memory");
    SB0();
    __builtin_amdgcn_s_setprio(1);
#pragma unroll
    for (int ks = 0; ks < 2; ++ks)
#pragma unroll
      for (int i = 0; i < 4; ++i)
#pragma unroll
        for (int j = 0; j < 2; ++j)
          acc[i + 4][j] = __builtin_amdgcn_mfma_f32_16x16x32_bf16(
              fa[i][ks], fb[j][ks], acc[i + 4][j], 0, 0, 0);
    __builtin_amdgcn_s_setprio(0);
    SB0();
    __builtin_amdgcn_s_barrier();

    // ---- phase 3: 0 ds_reads; stage B-h1(t+2); MFMA acc[4..7][2..3];
    //      counted vmcnt(4) -> A(t+1)+B(t+1) landed, B(t+2) in flight ----
    if (pfB) stageB(kt2, 1);
    SB0();
    __builtin_amdgcn_s_barrier();
    SB0();
    __builtin_amdgcn_s_setprio(1);
#pragma unroll
    for (int ks = 0; ks < 2; ++ks)
#pragma unroll
      for (int i = 0; i < 4; ++i)
#pragma unroll
        for (int j = 0; j < 2; ++j)
          acc[i + 4][j + 2] = __builtin_amdgcn_mfma_f32_16x16x32_bf16(
              fa[i][ks], fb[j + 2][ks], acc[i + 4][j + 2], 0, 0, 0);
    __builtin_amdgcn_s_setprio(0);
    SB0();
    if (t < NT - 2) {
      asm volatile("s_waitcnt vmcnt(4)" ::: "memory");
    } else {
      // tail: no B(t+2) staged; everything needed must drain
      asm volatile("s_waitcnt vmcnt(0)" ::: "memory");
    }
    __builtin_amdgcn_s_barrier();
  }

  // epilogue: C/D layout col=lane&15, row=quad*4+reg; f32 out
  const int r0 = m0 + (wm << 7) + (quad << 2);
  const int c0 = n0 + (wn << 6) + lr;
#pragma unroll
  for (int i = 0; i < 8; ++i)
#pragma unroll
    for (int j = 0; j < 4; ++j)
#pragma unroll
      for (int r = 0; r < 4; ++r)
        C[(size_t)(r0 + i * 16 + r) * OUT_F + (c0 + j * 16)] = acc[i][j][r];
#undef RDA
#undef RDB
}

// ------- GEMM (fallback, round-3 passing kernel): X f32, W bf16 -----------
__global__ __launch_bounds__(256) void gemm_fb(
    const float* __restrict__ X, const bf16_t* __restrict__ W,
    float* __restrict__ C) {
  __shared__ __align__(16) bf16_t Asf[BM * BK];
  __shared__ __align__(16) bf16_t Bsf[BN * BK];

  const int tid = threadIdx.x;
  const int lane = tid & 63;
  const int wid = tid >> 6;
  const int m0 = blockIdx.y * BM;
  const int n0 = blockIdx.x * BN;

  const int srow = tid >> 2;
  const int sk = (tid & 3) << 3;
  const float* ag0 = X + (size_t)(m0 + srow) * IN_F + sk;
  const float* ag1 = ag0 + (size_t)64 * IN_F;
  const bf16_t* bg0 = W + (size_t)(n0 + srow) * IN_F + sk;
  const bf16_t* bg1 = bg0 + (size_t)64 * IN_F;
  bf16_t* as0 = Asf + srow * BK + sk;
  bf16_t* as1 = as0 + 64 * BK;
  bf16_t* bs0 = Bsf + srow * BK + sk;
  bf16_t* bs1 = bs0 + 64 * BK;

  const int wmf = (wid >> 1) << 6;
  const int wnf = (wid & 1) << 6;
  const int lrf = lane & 15;
  const int quadf = lane >> 4;

  f32x4 acc[4][4] = {};

  for (int k0 = 0; k0 < IN_F; k0 += BK) {
    f32x4 xa0 = *(const f32x4*)(ag0 + k0);
    f32x4 xa1 = *(const f32x4*)(ag0 + k0 + 4);
    f32x4 xb0 = *(const f32x4*)(ag1 + k0);
    f32x4 xb1 = *(const f32x4*)(ag1 + k0 + 4);
    bf16x8 rb0 = *(const bf16x8*)(bg0 + k0);
    bf16x8 rb1 = *(const bf16x8*)(bg1 + k0);

    bf16x8 ra0, ra1;
#pragma unroll
    for (int t = 0; t < 4; ++t) {
      ra0[t] = (bf16_t)xa0[t];
      ra0[t + 4] = (bf16_t)xa1[t];
      ra1[t] = (bf16_t)xb0[t];
      ra1[t + 4] = (bf16_t)xb1[t];
    }

    __syncthreads();
    *(bf16x8*)as0 = ra0;
    *(bf16x8*)as1 = ra1;
    *(bf16x8*)bs0 = rb0;
    *(bf16x8*)bs1 = rb1;
    __syncthreads();

    bf16x8 fa[4], fbv[4];
#pragma unroll
    for (int i = 0; i < 4; ++i)
      fa[i] = *(const bf16x8*)(Asf + (wmf + i * 16 + lrf) * BK + quadf * 8);
#pragma unroll
    for (int j = 0; j < 4; ++j)
      fbv[j] = *(const bf16x8*)(Bsf + (wnf + j * 16 + lrf) * BK + quadf * 8);

#pragma unroll
    for (int i = 0; i < 4; ++i)
#pragma unroll
      for (int j = 0; j < 4; ++j)
        acc[i][j] = __builtin_amdgcn_mfma_f32_16x16x32_bf16(
            fa[i], fbv[j], acc[i][j], 0, 0, 0);
  }

#pragma unroll
  for (int i = 0; i < 4; ++i)
#pragma unroll
    for (int j = 0; j < 4; ++j)
#pragma unroll
      for (int r = 0; r < 4; ++r) {
        const int row = m0 + wmf + i * 16 + (quadf << 2) + r;
        const int col = n0 + wnf + j * 16 + lrf;
        C[(size_t)row * OUT_F + col] = acc[i][j][r];
      }
}

extern "C" void kernel_launch(void* const* d_in, const int* in_sizes, int n_in,
                              void* d_out, int out_size, void* d_ws, size_t ws_size,
                              hipStream_t stream) {
  const float* x   = (const float*)d_in[0];   // fp16 in reference -> f32 here
  const int* qw    = (const int*)d_in[1];
  const int* am1   = (const int*)d_in[2];
  const float* cd1 = (const float*)d_in[3];
  const float* of1 = (const float*)d_in[4];
  const float* am2 = (const float*)d_in[5];
  const float* cd2 = (const float*)d_in[6];
  float* out = (float*)d_out;                 // fp16 in reference -> f32 here

  const size_t W_BYTES  = (size_t)OUT_F * IN_F * 2;   // 32 MiB
  const size_t XB_BYTES = (size_t)TOKENS * IN_F * 2;  // 64 MiB
  bf16_t* W = (bf16_t*)d_ws;

  dequant_nf4<<<dim3((OUT_F * IN_F) / 8 / 256), dim3(256), 0, stream>>>(
      qw, am1, cd1, of1, am2, cd2, W);

  if (ws_size >= W_BYTES + XB_BYTES) {
    // fast path: pre-convert X to bf16, 256^2 4-phase GEMM (m201 template +
    // B-early-stagger deep prefetch)
    bf16_t* Xb = (bf16_t*)((char*)d_ws + W_BYTES);
    conv_x<<<dim3((TOKENS * IN_F) / 8 / 256), dim3(256), 0, stream>>>(x, Xb);
    gemm_8p<<<dim3((TOKENS / 256) * (OUT_F / 256)), dim3(512), 0, stream>>>(
        Xb, W, out);
  } else {
    // fallback: round-3 passing kernel (f32 X converted at staging)
    dim3 grid(OUT_F / BN, TOKENS / BM);
    gemm_fb<<<grid, dim3(256), 0, stream>>>(x, W, out);
  }
}

// Round 5
// 467.209 us; speedup vs baseline: 1.0250x; 1.0056x over previous
//
#include <hip/hip_runtime.h>
#include <hip/hip_bf16.h>
#include <cstdint>
#include <cstddef>

typedef __bf16 bf16_t;
typedef __bf16 bf16x8 __attribute__((ext_vector_type(8)));
typedef float f32x4 __attribute__((ext_vector_type(4)));

#define TOKENS 8192
#define IN_F 4096
#define OUT_F 4096

// fallback (128^2) geometry
#define BM 128
#define BN 128
#define BK 32

// 256^2 geometry
#define GK 64
#define NT (IN_F / GK)   // 64 K-tiles

// async global->LDS, 16B per lane; LDS dest is wave-uniform base + lane*16
#define GLDS(gp, lp)                                                      \
  __builtin_amdgcn_global_load_lds(                                       \
      (__attribute__((address_space(1))) void*)(gp),                      \
      (__attribute__((address_space(3))) void*)(lp), 16, 0, 0)

#define SB0() __builtin_amdgcn_sched_barrier(0)

// ---------------- dequant: packed nibbles -> bf16 W[OUT_F][IN_F] ----------
__global__ __launch_bounds__(256) void dequant_nf4(
    const int* __restrict__ qw, const int* __restrict__ am1,
    const float* __restrict__ cd1, const float* __restrict__ of1,
    const float* __restrict__ am2, const float* __restrict__ cd2,
    bf16_t* __restrict__ W) {
  const int t = blockIdx.x * 256 + threadIdx.x;
  const int e0 = t << 3;        // 8 dequantized elements per thread
  const int b1 = e0 >> 6;       // primary block (64 elems) -- all 8 share it
  const int b2 = e0 >> 8;       // secondary block (256 elems)
  const int4 v = *(const int4*)(qw + (t << 2));
  const float s2 = am2[b2] / cd2[b2];
  const float s1 = ((float)am1[b1] / cd1[b1]) * s2;
  const float off = of1[b1];
  int vv[4] = {v.x, v.y, v.z, v.w};
  bf16x8 w;
#pragma unroll
  for (int i = 0; i < 4; ++i) {
    w[2 * i]     = (bf16_t)(((float)(vv[i] & 15) - off) * s1);
    w[2 * i + 1] = (bf16_t)(((float)((vv[i] >> 4) & 15) - off) * s1);
  }
  *(bf16x8*)(W + e0) = w;
}

// ---------------- X: f32 -> bf16 one-shot convert -------------------------
__global__ __launch_bounds__(256) void conv_x(
    const float* __restrict__ X, bf16_t* __restrict__ Xb) {
  const size_t e0 = ((size_t)blockIdx.x * 256 + threadIdx.x) << 3;
  f32x4 a = *(const f32x4*)(X + e0);
  f32x4 b = *(const f32x4*)(X + e0 + 4);
  bf16x8 w;
#pragma unroll
  for (int i = 0; i < 4; ++i) {
    w[i] = (bf16_t)a[i];
    w[i + 4] = (bf16_t)b[i];
  }
  *(bf16x8*)(Xb + e0) = w;
}

// ======== GEMM: 256x256 tile, BK=64, 8-wave, decoupled 8-sub-phase ========
// C[M,N] = Xb[M,K]*W[N,K]^T. Sub-phase s issues ds_reads for s+1's frags,
// MFMAs consume s-1's reads (compiler emits counted lgkmcnt) -> LDS pipe
// (~2260 cyc/tile) overlaps MFMA pipe (~2360 cyc/tile). 2 barriers/tile.
//
// Round-5 fixes vs round-4 (failed, absmax 9344):
//  (1) B staging lost its (w&1)<<5 column-half -> odd k-subtiles staged
//      wrong columns. Restored as gcolB.
//  (2) stageB(t+2,h0) was issued between P0/P2 while other waves' s2
//      ds_reads of B(t) (same region) are also between P0/P2 -> WAR race.
//      Moved after P2 barrier; P2 wait vmcnt(4) -> vmcnt(2).
//  (3) restored final vmcnt(0) drain before epilogue (in-flight GLDS at
//      endpgm is UB).
//
// LDS: A[2 buf][wm:2][R:8][Cb:2][1024B subtile], B analogous.
// st_16x32 swizzle via pre-swizzled global source + XOR'd read (rule #21).
// A halves INTERLEAVED: h0 = R0-3 both wm (rows 0-63 & 128-191), h1 = R4-7.
//
// Per tile t (buf b), sub-phases:
//  s0: rd{fa lo ks1, fb_lo ks1}             | MFMA Q0ks0
//  s1: rd{fb_hi ks0}                        | MFMA Q0ks1
//      stageA(t+1)h0 ; vmcnt(6) ; barrier   [P0] (drains A(t)h1)
//  s2: rd{fb_hi ks1}                        | MFMA Q1ks0
//  s3: rd{fa hi ks0}                        | MFMA Q1ks1 ; stageA(t+1)h1
//  s4: rd{fa hi ks1}                        | MFMA Q2ks0
//  s5:                                      | MFMA Q2ks1
//      vmcnt(2) ; barrier                   [P2] (drains A(t+1)h0+B(t+1),
//                                                leaves A(t+1)h1)
//  s6: stageB(t+2)h0                        | MFMA Q3ks0
//  s7: rd{fa<-A(t+1)lo ks0, fb_lo<-B(t+1)}  | MFMA Q3ks1 ; stageB(t+2)h1
// Wrap-staging (kt&63) keeps counts uniform at the tail; stale tail
// stages write only never-again-read buffers.
__global__ __launch_bounds__(512) void gemm_8p(
    const bf16_t* __restrict__ X, const bf16_t* __restrict__ Wq,
    float* __restrict__ C) {
  __shared__ __align__(16) bf16_t smem[65536];   // 128 KiB
  bf16_t* const As = smem;            // 2 bufs x 32 KB
  bf16_t* const Bs = smem + 32768;

  const int tid  = threadIdx.x;
  const int l    = tid & 63;
  const int w    = tid >> 6;          // 8 waves
  const int wm   = w >> 2;            // 2 along M (128 rows each)
  const int wn   = w & 3;             // 4 along N (64 cols each)
  const int lr   = l & 15;
  const int quad = l >> 4;

  // T1: XCD-aware bijective swizzle (nwg=512, 512%8==0)
  const int swz = (blockIdx.x & 7) * 64 + (blockIdx.x >> 3);
  const int m0 = (swz >> 4) * 256;    // 32 m-tiles
  const int n0 = (swz & 15) * 256;    // 16 n-tiles

  // inverse st_16x32 swizzle on the global source column
  const int gcolA = ((l & 3) << 3) ^ ((l & 32) ? 16 : 0);
  const int gcolB = ((w & 1) << 5) + gcolA;   // FIX (1): col-half for B

  // ---- A staging: wave w -> wm=w>>2, R=4h+(w&3); 2 GLDS = Cb 0,1 ----
  const int awm = w >> 2;
  const int ar  = w & 3;
  const bf16_t* const gAs =
      X + (size_t)(m0 + awm * 128 + ar * 16 + (l >> 2)) * IN_F + gcolA;
  auto stageA = [&](int kt, int h) {
    const bf16_t* s = gAs + (size_t)(h * 64) * IN_F + kt * GK;
    bf16_t* d = As + ((kt & 1) << 14) +
                (((awm << 4) | (((h << 2) + ar) << 1)) << 9);
    GLDS(s, d);            // Cb=0
    GLDS(s + 32, d + 512); // Cb=1
  };

  // ---- B staging: wave w -> rows 16*(w>>1)+.. and +64 of col-half (w&1),
  //      row-half h; writes subtiles w and w+8 of buf's h-region ----
  const int grow = ((w >> 1) << 4) + (l >> 2);
  const bf16_t* const gB = Wq + (size_t)(n0 + grow) * IN_F + gcolB;
  auto stageB = [&](int kt, int h) {
    const bf16_t* s = gB + (size_t)(h * 128) * IN_F + kt * GK;
    bf16_t* d = Bs + ((kt & 1) << 14) + (h << 13) + (w << 9);
    GLDS(s, d);
    GLDS(s + (size_t)64 * IN_F, d + 4096);
  };

  // ---- read addressing (byte offsets; swizzled) ----
  const int rdoff = ((lr << 6) + (quad << 4)) ^ ((lr & 8) ? 32 : 0);
  const char* const aRd = (const char*)As + (wm << 14) + rdoff;
  const char* const bRd =
      (const char*)Bs + ((wn >> 1) << 14) + ((wn & 1) << 13) + rdoff;

  f32x4 acc[8][4];
#pragma unroll
  for (int i = 0; i < 8; ++i)
#pragma unroll
    for (int j = 0; j < 4; ++j) acc[i][j] = (f32x4){0.f, 0.f, 0.f, 0.f};

  bf16x8 fa[4][2], fb_lo[2][2], fb_hi[2][2];

// MFMA cluster: 8 mfma into acc[AI..AI+3][BI..BI+1]
#define CL(AI, BI, FAK, FB, FBK)                                          \
  __builtin_amdgcn_s_setprio(1);                                          \
  _Pragma("unroll") for (int i = 0; i < 4; ++i)                           \
      _Pragma("unroll") for (int j = 0; j < 2; ++j)                       \
          acc[(AI) + i][(BI) + j] =                                       \
              __builtin_amdgcn_mfma_f32_16x16x32_bf16(                    \
                  fa[i][FAK], FB[j][FBK], acc[(AI) + i][(BI) + j], 0, 0,  \
                  0);                                                     \
  __builtin_amdgcn_s_setprio(0);                                          \
  SB0();

  // ---- prologue: stage A(0) h0+h1, B(0) h0+h1, B(1) h0+h1; drain all
  // but B(1) (vmcnt(4)); barrier; then "s7(-1)" reads: A(0)lo ks0, B(0) ks0
  stageA(0, 0); stageA(0, 1); stageB(0, 0); stageB(0, 1);
  stageB(1, 0); stageB(1, 1);
  asm volatile("s_waitcnt vmcnt(4)" ::: "memory");
  SB0();
  __builtin_amdgcn_s_barrier();
#pragma unroll
  for (int i = 0; i < 4; ++i)
    fa[i][0] = *(const bf16x8*)(aRd + (i << 11));
#pragma unroll
  for (int j = 0; j < 2; ++j)
    fb_lo[j][0] = *(const bf16x8*)(bRd + (j << 11));
  SB0();

  for (int t = 0; t < NT; ++t) {
    const int b = t & 1;
    const int kt1 = (t + 1) & (NT - 1);   // wrap: stale tail stages, safe
    const int kt2 = (t + 2) & (NT - 1);
    const char* aB  = aRd + (b << 15);
    const char* aB1 = aRd + ((b ^ 1) << 15);
    const char* bB  = bRd + (b << 15);
    const char* bB1 = bRd + ((b ^ 1) << 15);

    // ---- s0: rd{fa ks1 (lo), fb_lo ks1}; MFMA Q0ks0 ----
#pragma unroll
    for (int i = 0; i < 4; ++i)
      fa[i][1] = *(const bf16x8*)(aB + (i << 11) + 1024);
#pragma unroll
    for (int j = 0; j < 2; ++j)
      fb_lo[j][1] = *(const bf16x8*)(bB + (j << 11) + 1024);
    SB0();
    CL(0, 0, 0, fb_lo, 0)

    // ---- s1: rd{fb_hi ks0}; MFMA Q0ks1; stage A(t+1)h0; P0 ----
#pragma unroll
    for (int j = 0; j < 2; ++j)
      fb_hi[j][0] = *(const bf16x8*)(bB + ((j + 2) << 11));
    SB0();
    CL(0, 0, 1, fb_lo, 1)

    stageA(kt1, 0);
    asm volatile("s_waitcnt vmcnt(6)" ::: "memory");   // drains A(t)h1
    SB0();
    __builtin_amdgcn_s_barrier();                      // P0

    // ---- s2: rd{fb_hi ks1}; MFMA Q1ks0 ----
#pragma unroll
    for (int j = 0; j < 2; ++j)
      fb_hi[j][1] = *(const bf16x8*)(bB + ((j + 2) << 11) + 1024);
    SB0();
    CL(0, 2, 0, fb_hi, 0)

    // ---- s3: rd{fa ks0 (hi)}; MFMA Q1ks1; stage A(t+1)h1 ----
#pragma unroll
    for (int i = 0; i < 4; ++i)
      fa[i][0] = *(const bf16x8*)(aB + ((i + 4) << 11));
    SB0();
    CL(0, 2, 1, fb_hi, 1)

    stageA(kt1, 1);

    // ---- s4: rd{fa ks1 (hi)}; MFMA Q2ks0 ----
#pragma unroll
    for (int i = 0; i < 4; ++i)
      fa[i][1] = *(const bf16x8*)(aB + ((i + 4) << 11) + 1024);
    SB0();
    CL(4, 0, 0, fb_lo, 0)

    // ---- s5: MFMA Q2ks1; P2 ----
    CL(4, 0, 1, fb_lo, 1)

    asm volatile("s_waitcnt vmcnt(2)" ::: "memory");   // A(t+1)h0 + B(t+1)
    SB0();
    __builtin_amdgcn_s_barrier();                      // P2

    // ---- s6: stage B(t+2)h0 (after P2: WAR-safe vs s2 reads); Q3ks0 ----
    stageB(kt2, 0);
    CL(4, 2, 0, fb_hi, 0)

    // ---- s7: rd{fa ks0 <- A(t+1)lo, fb_lo ks0 <- B(t+1)}; MFMA Q3ks1;
    //      stage B(t+2)h1 ----
#pragma unroll
    for (int i = 0; i < 4; ++i)
      fa[i][0] = *(const bf16x8*)(aB1 + (i << 11));
#pragma unroll
    for (int j = 0; j < 2; ++j)
      fb_lo[j][0] = *(const bf16x8*)(bB1 + (j << 11));
    SB0();
    CL(4, 2, 1, fb_hi, 1)

    stageB(kt2, 1);
  }
#undef CL

  // FIX (3): drain in-flight GLDS before endpgm/epilogue
  asm volatile("s_waitcnt vmcnt(0)" ::: "memory");
  SB0();

  // epilogue: C/D layout col=lane&15, row=quad*4+reg; f32 out
  const int r0 = m0 + (wm << 7) + (quad << 2);
  const int c0 = n0 + (wn << 6) + lr;
#pragma unroll
  for (int i = 0; i < 8; ++i)
#pragma unroll
    for (int j = 0; j < 4; ++j)
#pragma unroll
      for (int r = 0; r < 4; ++r)
        C[(size_t)(r0 + i * 16 + r) * OUT_F + (c0 + j * 16)] = acc[i][j][r];
}

// ------- GEMM (fallback, round-3 passing kernel): X f32, W bf16 -----------
__global__ __launch_bounds__(256) void gemm_fb(
    const float* __restrict__ X, const bf16_t* __restrict__ W,
    float* __restrict__ C) {
  __shared__ __align__(16) bf16_t Asf[BM * BK];
  __shared__ __align__(16) bf16_t Bsf[BN * BK];

  const int tid = threadIdx.x;
  const int lane = tid & 63;
  const int wid = tid >> 6;
  const int m0 = blockIdx.y * BM;
  const int n0 = blockIdx.x * BN;

  const int srow = tid >> 2;
  const int sk = (tid & 3) << 3;
  const float* ag0 = X + (size_t)(m0 + srow) * IN_F + sk;
  const float* ag1 = ag0 + (size_t)64 * IN_F;
  const bf16_t* bg0 = W + (size_t)(n0 + srow) * IN_F + sk;
  const bf16_t* bg1 = bg0 + (size_t)64 * IN_F;
  bf16_t* as0 = Asf + srow * BK + sk;
  bf16_t* as1 = as0 + 64 * BK;
  bf16_t* bs0 = Bsf + srow * BK + sk;
  bf16_t* bs1 = bs0 + 64 * BK;

  const int wmf = (wid >> 1) << 6;
  const int wnf = (wid & 1) << 6;
  const int lrf = lane & 15;
  const int quadf = lane >> 4;

  f32x4 acc[4][4] = {};

  for (int k0 = 0; k0 < IN_F; k0 += BK) {
    f32x4 xa0 = *(const f32x4*)(ag0 + k0);
    f32x4 xa1 = *(const f32x4*)(ag0 + k0 + 4);
    f32x4 xb0 = *(const f32x4*)(ag1 + k0);
    f32x4 xb1 = *(const f32x4*)(ag1 + k0 + 4);
    bf16x8 rb0 = *(const bf16x8*)(bg0 + k0);
    bf16x8 rb1 = *(const bf16x8*)(bg1 + k0);

    bf16x8 ra0, ra1;
#pragma unroll
    for (int t = 0; t < 4; ++t) {
      ra0[t] = (bf16_t)xa0[t];
      ra0[t + 4] = (bf16_t)xa1[t];
      ra1[t] = (bf16_t)xb0[t];
      ra1[t + 4] = (bf16_t)xb1[t];
    }

    __syncthreads();
    *(bf16x8*)as0 = ra0;
    *(bf16x8*)as1 = ra1;
    *(bf16x8*)bs0 = rb0;
    *(bf16x8*)bs1 = rb1;
    __syncthreads();

    bf16x8 fa[4], fbv[4];
#pragma unroll
    for (int i = 0; i < 4; ++i)
      fa[i] = *(const bf16x8*)(Asf + (wmf + i * 16 + lrf) * BK + quadf * 8);
#pragma unroll
    for (int j = 0; j < 4; ++j)
      fbv[j] = *(const bf16x8*)(Bsf + (wnf + j * 16 + lrf) * BK + quadf * 8);

#pragma unroll
    for (int i = 0; i < 4; ++i)
#pragma unroll
      for (int j = 0; j < 4; ++j)
        acc[i][j] = __builtin_amdgcn_mfma_f32_16x16x32_bf16(
            fa[i], fbv[j], acc[i][j], 0, 0, 0);
  }

#pragma unroll
  for (int i = 0; i < 4; ++i)
#pragma unroll
    for (int j = 0; j < 4; ++j)
#pragma unroll
      for (int r = 0; r < 4; ++r) {
        const int row = m0 + wmf + i * 16 + (quadf << 2) + r;
        const int col = n0 + wnf + j * 16 + lrf;
        C[(size_t)row * OUT_F + col] = acc[i][j][r];
      }
}

extern "C" void kernel_launch(void* const* d_in, const int* in_sizes, int n_in,
                              void* d_out, int out_size, void* d_ws, size_t ws_size,
                              hipStream_t stream) {
  const float* x   = (const float*)d_in[0];   // fp16 in reference -> f32 here
  const int* qw    = (const int*)d_in[1];
  const int* am1   = (const int*)d_in[2];
  const float* cd1 = (const float*)d_in[3];
  const float* of1 = (const float*)d_in[4];
  const float* am2 = (const float*)d_in[5];
  const float* cd2 = (const float*)d_in[6];
  float* out = (float*)d_out;                 // fp16 in reference -> f32 here

  const size_t W_BYTES  = (size_t)OUT_F * IN_F * 2;   // 32 MiB
  const size_t XB_BYTES = (size_t)TOKENS * IN_F * 2;  // 64 MiB
  bf16_t* W = (bf16_t*)d_ws;

  dequant_nf4<<<dim3((OUT_F * IN_F) / 8 / 256), dim3(256), 0, stream>>>(
      qw, am1, cd1, of1, am2, cd2, W);

  if (ws_size >= W_BYTES + XB_BYTES) {
    // fast path: pre-convert X to bf16, 256^2 decoupled-sub-phase GEMM
    bf16_t* Xb = (bf16_t*)((char*)d_ws + W_BYTES);
    conv_x<<<dim3((TOKENS * IN_F) / 8 / 256), dim3(256), 0, stream>>>(x, Xb);
    gemm_8p<<<dim3((TOKENS / 256) * (OUT_F / 256)), dim3(512), 0, stream>>>(
        Xb, W, out);
  } else {
    // fallback: round-3 passing kernel (f32 X converted at staging)
    dim3 grid(OUT_F / BN, TOKENS / BM);
    gemm_fb<<<grid, dim3(256), 0, stream>>>(x, W, out);
  }
}